// Round 11
// baseline (418.402 us; speedup 1.0000x reference)
//
#include <hip/hip_runtime.h>
#include <hip/hip_bf16.h>
#include <float.h>
#include <math.h>

#define HEADS 16
#define HD 64
#define DIM 1024
#define NTOK 4096
#define QKVN 3072

typedef short s8v __attribute__((ext_vector_type(8)));   // 8 bf16 bit-patterns (4 VGPR)
typedef float f4v __attribute__((ext_vector_type(4)));   // MFMA accumulator

static __device__ __forceinline__ unsigned short f2b(float f) {
  __hip_bfloat16 h = __float2bfloat16(f);
  unsigned short u;
  __builtin_memcpy(&u, &h, 2);
  return u;
}
static __device__ __forceinline__ s8v pack_bf8(float4 a, float4 b) {
  s8v r;
  r[0] = (short)f2b(a.x); r[1] = (short)f2b(a.y); r[2] = (short)f2b(a.z); r[3] = (short)f2b(a.w);
  r[4] = (short)f2b(b.x); r[5] = (short)f2b(b.y); r[6] = (short)f2b(b.z); r[7] = (short)f2b(b.w);
  return r;
}
// async global->LDS, 16B per lane (HW: wave-uniform base + lane*16)
static __device__ __forceinline__ void gload16(const unsigned short* g, unsigned short* l) {
  __builtin_amdgcn_global_load_lds(
      (const __attribute__((address_space(1))) void*)g,
      (__attribute__((address_space(3))) void*)l, 16, 0, 0);
}

// ---------------------------------------------------------------------------
// Cast fp32 -> bf16, 8 elems/thread.
// ---------------------------------------------------------------------------
__global__ __launch_bounds__(256) void cast_f2b(const float* __restrict__ in,
                                                unsigned short* __restrict__ out) {
  const int i = (blockIdx.x * 256 + threadIdx.x) * 8;
  float4 a = *(const float4*)(in + i);
  float4 b = *(const float4*)(in + i + 4);
  *(s8v*)(out + i) = pack_bf8(a, b);
}

// ---------------------------------------------------------------------------
// Transpose + cast: fp32 [K][N] -> bf16 [N][K]. 32x32 tiles, 256 threads.
// ---------------------------------------------------------------------------
__global__ __launch_bounds__(256) void transpose_f2b(const float* __restrict__ in,
                                                     unsigned short* __restrict__ out,
                                                     int K, int N) {
  __shared__ unsigned short T[32][36];
  const int k0 = blockIdx.y * 32, n0 = blockIdx.x * 32;
  const int t = threadIdx.x;
  const int r = t >> 3, c4 = (t & 7) * 4;
  float4 f = *(const float4*)(in + (size_t)(k0 + r) * N + n0 + c4);
  T[r][c4 + 0] = f2b(f.x);
  T[r][c4 + 1] = f2b(f.y);
  T[r][c4 + 2] = f2b(f.z);
  T[r][c4 + 3] = f2b(f.w);
  __syncthreads();
  ushort4 o;
  o.x = T[c4 + 0][r];
  o.y = T[c4 + 1][r];
  o.z = T[c4 + 2][r];
  o.w = T[c4 + 3][r];
  *(ushort4*)(out + (size_t)(n0 + r) * K + k0 + c4) = o;
}

// ---------------------------------------------------------------------------
// GEMM: C[M][N] = A[M][K] (bf16) @ Bt[N][K]^T (bf16). 128x128 tile, BK=32,
// 4 waves, mfma_f32_16x16x32_bf16, linear LDS + global_load_lds w16.
// (Validated R8.)
// ---------------------------------------------------------------------------
template <int OUT_F32, int RELU>
__global__ __launch_bounds__(256) void gemm_bb(const unsigned short* __restrict__ A,
                                               const unsigned short* __restrict__ Bt,
                                               void* __restrict__ Cv,
                                               int M, int N, int K) {
  __shared__ __align__(16) unsigned short As[128 * 32];
  __shared__ __align__(16) unsigned short Bs[128 * 32];
  const int t = threadIdx.x;
  const int wave = t >> 6, lane = t & 63;
  const int wr = wave >> 1, wc = wave & 1;
  const int g = lane >> 4, c = lane & 15;
  const int m0 = blockIdx.y * 128, n0 = blockIdx.x * 128;

  const int sr = t >> 2;        // staging row 0..63 (and +64)
  const int sc = (t & 3) * 8;   // staging col (bf16 elems), 16B chunks

  const unsigned short* a0p = A + (size_t)(m0 + sr) * K + sc;
  const unsigned short* a1p = A + (size_t)(m0 + sr + 64) * K + sc;
  const unsigned short* b0p = Bt + (size_t)(n0 + sr) * K + sc;
  const unsigned short* b1p = Bt + (size_t)(n0 + sr + 64) * K + sc;
  unsigned short* lA0 = As + t * 8;
  unsigned short* lA1 = As + 2048 + t * 8;
  unsigned short* lB0 = Bs + t * 8;
  unsigned short* lB1 = Bs + 2048 + t * 8;

  f4v acc[4][4] = {};

  for (int k0 = 0; k0 < K; k0 += 32) {
    __syncthreads();
    gload16(a0p + k0, lA0);
    gload16(a1p + k0, lA1);
    gload16(b0p + k0, lB0);
    gload16(b1p + k0, lB1);
    __syncthreads();
    s8v af[4], bf[4];
#pragma unroll
    for (int m = 0; m < 4; ++m) af[m] = *(const s8v*)&As[(wr * 64 + m * 16 + c) * 32 + g * 8];
#pragma unroll
    for (int n = 0; n < 4; ++n) bf[n] = *(const s8v*)&Bs[(wc * 64 + n * 16 + c) * 32 + g * 8];
#pragma unroll
    for (int m = 0; m < 4; ++m)
#pragma unroll
      for (int n = 0; n < 4; ++n)
        acc[m][n] = __builtin_amdgcn_mfma_f32_16x16x32_bf16(af[m], bf[n], acc[m][n], 0, 0, 0);
  }

#pragma unroll
  for (int m = 0; m < 4; ++m)
#pragma unroll
    for (int n = 0; n < 4; ++n)
#pragma unroll
      for (int r = 0; r < 4; ++r) {
        const int row = m0 + wr * 64 + m * 16 + g * 4 + r;
        const int col = n0 + wc * 64 + n * 16 + c;
        float v = acc[m][n][r];
        if (RELU) v = fmaxf(v, 0.f);
        if (OUT_F32)
          ((float*)Cv)[(size_t)row * N + col] = v;
        else
          ((unsigned short*)Cv)[(size_t)row * N + col] = f2b(v);
      }
}

// ---------------------------------------------------------------------------
// RoPE in-place on bf16 qkv [NTOK][3072]; Q pre-scaled by 0.125. (Valid R8.)
// ---------------------------------------------------------------------------
__global__ __launch_bounds__(512) void rope64_kernel(unsigned short* __restrict__ qkv) {
  __shared__ float cs[32], sn[32];
  const int i = blockIdx.x;
  const int t = threadIdx.x;
  if (t < 32) {
    const double inv = pow(10000.0, -(double)t / 32.0);
    double sd, cd;
    sincos((double)i * inv, &sd, &cd);
    cs[t] = (float)cd;
    sn[t] = (float)sd;
  }
  __syncthreads();
  const int h = t >> 5, j = t & 31;
  const float cc = cs[j], ss = sn[j];
  const size_t base = (size_t)i * QKVN + h * HD + j;
  const float qa = __bfloat162float(*(const __hip_bfloat16*)&qkv[base]);
  const float qb = __bfloat162float(*(const __hip_bfloat16*)&qkv[base + 32]);
  qkv[base] = f2b((qa * cc - qb * ss) * 0.125f);
  qkv[base + 32] = f2b((qb * cc + qa * ss) * 0.125f);
  const float ka = __bfloat162float(*(const __hip_bfloat16*)&qkv[base + DIM]);
  const float kb = __bfloat162float(*(const __hip_bfloat16*)&qkv[base + DIM + 32]);
  qkv[base + DIM] = f2b(ka * cc - kb * ss);
  qkv[base + DIM + 32] = f2b(kb * cc + ka * ss);
}

// ---------------------------------------------------------------------------
// MFMA flash attention (causal), QBLK=128. 512 blocks: h = bid&15,
// qi = 31-(bid>>4) (LPT), rows [qi*128, qi*128+128). 4 waves; wave w owns
// m-frags at rows q0 + m*64 + w*16 + {0..15} (m = 0,1).
// Per 64-row KV tile: async-split staging (T14: global->reg issued during
// previous tile's compute; reg->LDS write after barrier), QK^T / online
// softmax (defer-max THR=8) / PV as validated R5-R8. Fully-masked m-frags
// skipped (wave-uniform). Scale pre-folded into Q by RoPE.
// ---------------------------------------------------------------------------
__global__ __launch_bounds__(256) void attn_mfma(const unsigned short* __restrict__ qkv,
                                                 unsigned short* __restrict__ att) {
  __shared__ unsigned short Ks[64][72];
  __shared__ unsigned short Vt[64][72];
  __shared__ unsigned short Pl[4][32][72];
  const int bid = blockIdx.x;
  const int h = bid & 15;
  const int qi = 31 - (bid >> 4);  // biggest-first (LPT)
  const int t = threadIdx.x;
  const int w = t >> 6, lane = t & 63;
  const int g = lane >> 4, c = lane & 15;
  const int q0 = qi * 128;
  const int base0 = q0 + w * 16;           // m=0 frag rows
  const int base1 = q0 + 64 + w * 16;      // m=1 frag rows
  const int base_m[2] = {base0, base1};

  // Q fragments: qf[m][kf], row = base_m + c, k = kf*32 + g*8 + j
  s8v qf[2][2];
#pragma unroll
  for (int m = 0; m < 2; ++m)
#pragma unroll
    for (int kf = 0; kf < 2; ++kf)
      qf[m][kf] = *(const s8v*)(qkv + (size_t)(base_m[m] + c) * QKVN + h * HD + kf * 32 + g * 8);

  f4v O[2][4] = {};
  float mrow[2][4], lrow[2][4];
#pragma unroll
  for (int m = 0; m < 2; ++m)
#pragma unroll
    for (int r = 0; r < 4; ++r) { mrow[m][r] = -1e30f; lrow[m][r] = 0.f; }

  const int ntile = 2 * qi + 2;

  // staging-register addressing
  const int kr = t >> 3, kc = (t & 7) * 8;   // K: rows kr, kr+32, 16B chunk kc
  const int kg = t & 15, dc = t >> 4;        // V: kv rows 4kg..4kg+3, dims dc*4..+3
  s8v kreg0, kreg1;
  ushort4 vr0, vr1, vr2, vr3;
  {
    const unsigned short* kbp = qkv + (size_t)kr * QKVN + DIM + h * HD + kc;
    kreg0 = *(const s8v*)(kbp);
    kreg1 = *(const s8v*)(kbp + 32 * QKVN);
    const unsigned short* vb = qkv + (size_t)(4 * kg) * QKVN + 2 * DIM + h * HD + dc * 4;
    vr0 = *(const ushort4*)(vb);
    vr1 = *(const ushort4*)(vb + QKVN);
    vr2 = *(const ushort4*)(vb + 2 * QKVN);
    vr3 = *(const ushort4*)(vb + 3 * QKVN);
  }

  for (int tile = 0; tile < ntile; ++tile) {
    const int kv0 = tile * 64;
    __syncthreads();  // all waves done reading LDS from previous tile
    // --- write staged regs -> LDS ---
    *(s8v*)&Ks[kr][kc] = kreg0;
    *(s8v*)&Ks[kr + 32][kc] = kreg1;
    {
      const unsigned short* q0v = (const unsigned short*)&vr0;
      const unsigned short* q1v = (const unsigned short*)&vr1;
      const unsigned short* q2v = (const unsigned short*)&vr2;
      const unsigned short* q3v = (const unsigned short*)&vr3;
#pragma unroll
      for (int dl = 0; dl < 4; ++dl) {
        ushort4 u;
        u.x = q0v[dl]; u.y = q1v[dl]; u.z = q2v[dl]; u.w = q3v[dl];
        *(ushort4*)&Vt[dc * 4 + dl][kg * 4] = u;
      }
    }
    __syncthreads();
    // --- issue next tile's global loads (latency hides under compute) ---
    if (tile + 1 < ntile) {
      const int nv0 = kv0 + 64;
      const unsigned short* kbp = qkv + (size_t)(nv0 + kr) * QKVN + DIM + h * HD + kc;
      kreg0 = *(const s8v*)(kbp);
      kreg1 = *(const s8v*)(kbp + 32 * QKVN);
      const unsigned short* vb = qkv + (size_t)(nv0 + 4 * kg) * QKVN + 2 * DIM + h * HD + dc * 4;
      vr0 = *(const ushort4*)(vb);
      vr1 = *(const ushort4*)(vb + QKVN);
      vr2 = *(const ushort4*)(vb + 2 * QKVN);
      vr3 = *(const ushort4*)(vb + 3 * QKVN);
    }

    // --- per m-frag: QK^T, softmax, P write (skip fully-masked frags) ---
    f4v S[2][4];
    float rmax[2][4];
    bool act[2];
#pragma unroll
    for (int m = 0; m < 2; ++m) {
      act[m] = (kv0 <= base_m[m] + 15);
#pragma unroll
      for (int r = 0; r < 4; ++r) rmax[m][r] = -1e30f;
    }
#pragma unroll
    for (int m = 0; m < 2; ++m) {
      if (!act[m]) continue;
#pragma unroll
      for (int n = 0; n < 4; ++n) {
        S[m][n] = f4v{0.f, 0.f, 0.f, 0.f};
#pragma unroll
        for (int kf = 0; kf < 2; ++kf) {
          s8v kfr = *(const s8v*)&Ks[n * 16 + c][kf * 32 + g * 8];
          S[m][n] = __builtin_amdgcn_mfma_f32_16x16x32_bf16(qf[m][kf], kfr, S[m][n], 0, 0, 0);
        }
      }
      if (kv0 + 63 > base_m[m]) {  // partial mask (diagonal tiles only)
#pragma unroll
        for (int n = 0; n < 4; ++n)
#pragma unroll
          for (int r = 0; r < 4; ++r) {
            float s = S[m][n][r];
            const int col = kv0 + n * 16 + c;
            const int row = base_m[m] + 4 * g + r;
            s = (col > row) ? -1e30f : s;
            S[m][n][r] = s;
            rmax[m][r] = fmaxf(rmax[m][r], s);
          }
      } else {
#pragma unroll
        for (int n = 0; n < 4; ++n)
#pragma unroll
          for (int r = 0; r < 4; ++r) rmax[m][r] = fmaxf(rmax[m][r], S[m][n][r]);
      }
#pragma unroll
      for (int r = 0; r < 4; ++r) {
        rmax[m][r] = fmaxf(rmax[m][r], __shfl_xor(rmax[m][r], 1));
        rmax[m][r] = fmaxf(rmax[m][r], __shfl_xor(rmax[m][r], 2));
        rmax[m][r] = fmaxf(rmax[m][r], __shfl_xor(rmax[m][r], 4));
        rmax[m][r] = fmaxf(rmax[m][r], __shfl_xor(rmax[m][r], 8));
      }
    }

    // --- defer-max (T13, THR=8) ---
    bool upd = false;
#pragma unroll
    for (int m = 0; m < 2; ++m)
#pragma unroll
      for (int r = 0; r < 4; ++r) upd = upd || (rmax[m][r] > mrow[m][r] + 8.0f);
    if (__any((int)upd)) {
#pragma unroll
      for (int m = 0; m < 2; ++m)
#pragma unroll
        for (int r = 0; r < 4; ++r) {
          const float mn = fmaxf(mrow[m][r], rmax[m][r]);
          const float corr = __expf(mrow[m][r] - mn);
          mrow[m][r] = mn;
          lrow[m][r] *= corr;
#pragma unroll
          for (int n = 0; n < 4; ++n) O[m][n][r] *= corr;
        }
    }

    // --- P = exp(S - m) -> wave-private LDS; row sums ---
#pragma unroll
    for (int m = 0; m < 2; ++m) {
      if (!act[m]) continue;
      float rsum[4] = {0.f, 0.f, 0.f, 0.f};
#pragma unroll
      for (int n = 0; n < 4; ++n)
#pragma unroll
        for (int r = 0; r < 4; ++r) {
          const float p = __expf(S[m][n][r] - mrow[m][r]);
          rsum[r] += p;
          Pl[w][m * 16 + 4 * g + r][n * 16 + c] = f2b(p);
        }
#pragma unroll
      for (int r = 0; r < 4; ++r) {
        rsum[r] += __shfl_xor(rsum[r], 1);
        rsum[r] += __shfl_xor(rsum[r], 2);
        rsum[r] += __shfl_xor(rsum[r], 4);
        rsum[r] += __shfl_xor(rsum[r], 8);
        lrow[m][r] += rsum[r];
      }
    }

    // --- O += P V ---
#pragma unroll
    for (int m = 0; m < 2; ++m) {
      if (!act[m]) continue;
      s8v pf[2];
#pragma unroll
      for (int kf = 0; kf < 2; ++kf) pf[kf] = *(const s8v*)&Pl[w][m * 16 + c][kf * 32 + g * 8];
#pragma unroll
      for (int n = 0; n < 4; ++n)
#pragma unroll
        for (int kf = 0; kf < 2; ++kf) {
          s8v vf = *(const s8v*)&Vt[n * 16 + c][kf * 32 + g * 8];
          O[m][n] = __builtin_amdgcn_mfma_f32_16x16x32_bf16(pf[kf], vf, O[m][n], 0, 0, 0);
        }
    }
  }

  // --- epilogue: normalize, store bf16 ---
#pragma unroll
  for (int m = 0; m < 2; ++m) {
    float inv[4];
#pragma unroll
    for (int r = 0; r < 4; ++r) inv[r] = 1.f / lrow[m][r];
#pragma unroll
    for (int n = 0; n < 4; ++n)
#pragma unroll
      for (int r = 0; r < 4; ++r) {
        const int row = base_m[m] + 4 * g + r;
        att[(size_t)row * DIM + h * HD + n * 16 + c] = f2b(O[m][n][r] * inv[r]);
      }
  }
}

// ---------------------------------------------------------------------------
// LayerNorm over last dim (1024), fp32 in/out, gamma fp32. (Validated R4.)
// ---------------------------------------------------------------------------
__global__ __launch_bounds__(256) void layernorm_kernel(const float* __restrict__ x,
                                                        const float* __restrict__ gamma,
                                                        float* __restrict__ out) {
  const int row = blockIdx.x;
  const int t = threadIdx.x;
  const float4 v = ((const float4*)(x + (size_t)row * DIM))[t];
  float s = v.x + v.y + v.z + v.w;
  float ss = v.x * v.x + v.y * v.y + v.z * v.z + v.w * v.w;
#pragma unroll
  for (int off = 32; off > 0; off >>= 1) {
    s += __shfl_xor(s, off);
    ss += __shfl_xor(ss, off);
  }
  __shared__ float red[8];
  const int wave = t >> 6, lane = t & 63;
  if (lane == 0) {
    red[wave] = s;
    red[4 + wave] = ss;
  }
  __syncthreads();
  const float S = red[0] + red[1] + red[2] + red[3];
  const float SS = red[4] + red[5] + red[6] + red[7];
  const float mean = S * (1.f / 1024.f);
  const float var = SS * (1.f / 1024.f) - mean * mean;
  const float r = rsqrtf(var + 1e-5f);
  const float4 g4 = ((const float4*)gamma)[t];
  float4 o;
  o.x = (v.x - mean) * r * g4.x;
  o.y = (v.y - mean) * r * g4.y;
  o.z = (v.z - mean) * r * g4.z;
  o.w = (v.w - mean) * r * g4.w;
  ((float4*)(out + (size_t)row * DIM))[t] = o;
}

// ---------------------------------------------------------------------------
extern "C" void kernel_launch(void* const* d_in, const int* in_sizes, int n_in,
                              void* d_out, int out_size, void* d_ws, size_t ws_size,
                              hipStream_t stream) {
  const float* x = (const float*)d_in[0];      // fp32 [4096][1024]
  const float* Wqkv = (const float*)d_in[1];   // fp32 [1024][3072]
  const float* Wo1 = (const float*)d_in[2];    // fp32 [1024][1024]
  const float* Wo2 = (const float*)d_in[3];    // fp32 [1024][1024]
  const float* gamma = (const float*)d_in[4];  // fp32 [1024]
  float* out = (float*)d_out;                  // fp32 [4096][1024]

  char* wsb = (char*)d_ws;
  // workspace (bytes), peak 44,040,192 (identical plan to R8):
  unsigned short* xb = (unsigned short*)wsb;
  unsigned short* qkv = (unsigned short*)(wsb + 8388608ull);
  unsigned short* Wqkvt = (unsigned short*)(wsb + 33554432ull);
  unsigned short* Wo1t = (unsigned short*)(wsb + 39845888ull);
  unsigned short* Wo2t = (unsigned short*)(wsb + 41943040ull);
  unsigned short* att = (unsigned short*)wsb;
  unsigned short* h1 = (unsigned short*)(wsb + 8388608ull);
  float* h2 = (float*)(wsb + 16777216ull);

  // 0. casts: x -> bf16; weights -> bf16 [N][K]
  cast_f2b<<<NTOK * DIM / (256 * 8), 256, 0, stream>>>(x, xb);
  transpose_f2b<<<dim3(QKVN / 32, DIM / 32), 256, 0, stream>>>(Wqkv, Wqkvt, DIM, QKVN);
  transpose_f2b<<<dim3(DIM / 32, DIM / 32), 256, 0, stream>>>(Wo1, Wo1t, DIM, DIM);
  transpose_f2b<<<dim3(DIM / 32, DIM / 32), 256, 0, stream>>>(Wo2, Wo2t, DIM, DIM);
  // 1. qkv = xb @ W_qkv  (bf16 out)
  gemm_bb<0, 0><<<dim3(QKVN / 128, NTOK / 128), 256, 0, stream>>>(xb, Wqkvt, qkv, NTOK, QKVN, DIM);
  // 2. RoPE in-place on Q,K (Q pre-scaled by 1/8)
  rope64_kernel<<<NTOK, 512, 0, stream>>>(qkv);
  // 3. causal flash attention (QBLK=128, async-stage) -> att bf16
  attn_mfma<<<NTOK / 128 * HEADS, 256, 0, stream>>>(qkv, att);
  // 4. h1 = relu(att @ W_o1)  (bf16 out)
  gemm_bb<0, 1><<<dim3(DIM / 128, NTOK / 128), 256, 0, stream>>>(att, Wo1t, h1, NTOK, DIM, DIM);
  // 5. h2 = h1 @ W_o2  (fp32 out)
  gemm_bb<1, 0><<<dim3(DIM / 128, NTOK / 128), 256, 0, stream>>>(h1, Wo2t, h2, NTOK, DIM, DIM);
  // 6. layernorm -> out
  layernorm_kernel<<<NTOK, 256, 0, stream>>>(h2, gamma, out);
}